// Round 1
// baseline (1394.319 us; speedup 1.0000x reference)
//
#include <hip/hip_runtime.h>

#define BLOCK 256
#define ROWS 4
#define DD 64
#define JJ 16

__global__ __launch_bounds__(BLOCK) void net_circuit_kernel(
    const float* __restrict__ x, const float* __restrict__ Ws,
    const float* __restrict__ bs, float* __restrict__ out, int B)
{
    __shared__ float Wl[DD * JJ];   // Wl[d*16 + j] = Ws[(j>>2)*256 + d*4 + (j&3)]
    __shared__ float bsl[JJ];

    const int tid = threadIdx.x;

    for (int idx = tid; idx < DD * JJ; idx += BLOCK) {
        int d = idx >> 4, j = idx & 15;
        Wl[idx] = Ws[(j >> 2) * (DD * 4) + d * 4 + (j & 3)];
    }
    if (tid < JJ) bsl[tid] = bs[tid];
    __syncthreads();

    const long long base = (long long)blockIdx.x * (BLOCK * ROWS) + tid;

    float acc[ROWS][JJ];
    #pragma unroll
    for (int r = 0; r < ROWS; ++r)
        #pragma unroll
        for (int j = 0; j < JJ; ++j) acc[r][j] = 0.0f;

    const float4* __restrict__ x4 = reinterpret_cast<const float4*>(x);
    const float4* __restrict__ W4 = reinterpret_cast<const float4*>(Wl);

    #pragma unroll
    for (int c = 0; c < DD / 4; ++c) {
        float4 xv[ROWS];
        #pragma unroll
        for (int r = 0; r < ROWS; ++r) {
            long long row = base + (long long)r * BLOCK;
            xv[r] = (row < B) ? x4[row * (DD / 4) + c] : make_float4(0.f, 0.f, 0.f, 0.f);
        }
        #pragma unroll
        for (int q = 0; q < 4; ++q) {
            const int d = c * 4 + q;
            // uniform LDS reads: 4x float4 per d (broadcast, conflict-free)
            float4 wv[4];
            #pragma unroll
            for (int g = 0; g < 4; ++g) wv[g] = W4[d * 4 + g];
            const float* wf = reinterpret_cast<const float*>(wv);
            #pragma unroll
            for (int r = 0; r < ROWS; ++r) {
                float xs = (q == 0) ? xv[r].x : (q == 1) ? xv[r].y : (q == 2) ? xv[r].z : xv[r].w;
                #pragma unroll
                for (int j = 0; j < JJ; ++j) {
                    acc[r][j] = fmaf(xs, wf[j], acc[r][j]);
                }
            }
        }
    }

    #pragma unroll
    for (int r = 0; r < ROWS; ++r) {
        long long row = base + (long long)r * BLOCK;
        if (row >= B) continue;

        float h[JJ];
        #pragma unroll
        for (int j = 0; j < JJ; ++j) {
            float z = acc[r][j] + bsl[j];
            h[j] = 1.0f / (1.0f + __expf(-z));
        }

        // f(17) = f(18) = 1; iterate i = 16 .. 1:
        //   neg_i = (i==3 || i==7) ? 1 : 1 - h[i-1]
        //   f(i)  = h[i-1]*f(i+1) + neg_i*f(i+2)
        float f1 = 1.0f;  // f(i+1)
        float f2 = 1.0f;  // f(i+2)
        #pragma unroll
        for (int i = 16; i >= 1; --i) {
            float hj = h[i - 1];
            float neg = (i == 3 || i == 7) ? 1.0f : (1.0f - hj);
            float fi = fmaf(hj, f1, neg * f2);
            f2 = f1;
            f1 = fi;
        }
        out[row] = f1;
    }
}

extern "C" void kernel_launch(void* const* d_in, const int* in_sizes, int n_in,
                              void* d_out, int out_size, void* d_ws, size_t ws_size,
                              hipStream_t stream) {
    const float* x  = (const float*)d_in[0];
    const float* Ws = (const float*)d_in[1];
    const float* bs = (const float*)d_in[2];
    float* out = (float*)d_out;

    const int B = in_sizes[0] / DD;
    const int rows_per_block = BLOCK * ROWS;
    const int grid = (B + rows_per_block - 1) / rows_per_block;

    net_circuit_kernel<<<grid, BLOCK, 0, stream>>>(x, Ws, bs, out, B);
}

// Round 2
// 72.559 us; speedup vs baseline: 19.2164x; 19.2164x over previous
//
#include <hip/hip_runtime.h>

#define BLOCK 256
#define DD 64
#define JJ 16

__device__ __forceinline__ float f4c(const float4& v, int i) {
    return i == 0 ? v.x : i == 1 ? v.y : i == 2 ? v.z : v.w;
}

__global__ __launch_bounds__(BLOCK, 2) void net_circuit_kernel(
    const float* __restrict__ x, const float* __restrict__ Ws,
    const float* __restrict__ bs, float* __restrict__ out, int B)
{
    // W staged interleaved: original d -> slot dmap = (d&15)*4 + (d>>4).
    // Quad lanes (q=0..3) then read slots dd*4+q: byte offsets differ by 64B,
    // banks differ by 16 -> 2-way-per-bank (free, m136).
    __shared__ float Wl[DD * JJ];
    __shared__ __align__(16) float bsl[JJ];

    const int tid = threadIdx.x;
    for (int idx = tid; idx < DD * JJ; idx += BLOCK) {
        int d = idx >> 4, j = idx & 15;
        int qq = d >> 4, dd = d & 15;
        Wl[(dd * 4 + qq) * JJ + j] = Ws[(j >> 2) * (DD * 4) + d * 4 + (j & 3)];
    }
    if (tid < JJ) bsl[tid] = bs[tid];
    __syncthreads();

    const int q  = tid & 3;          // which 16-d quarter this lane owns
    const int rr = (tid >> 2) & 15;  // row-within-group
    const int wid = tid >> 6;
    const long long wave_base = (long long)blockIdx.x * 256 + (long long)wid * 64;
    const bool full = (wave_base + 64 <= (long long)B);

    const float4* __restrict__ x4 = reinterpret_cast<const float4*>(x);
    const float4* __restrict__ W4 = reinterpret_cast<const float4*>(Wl);

    float acc[4][JJ];
    #pragma unroll
    for (int r = 0; r < 4; ++r)
        #pragma unroll
        for (int j = 0; j < JJ; ++j) acc[r][j] = 0.0f;

    #pragma unroll
    for (int pass = 0; pass < 2; ++pass) {
        // load this pass's 8 d-values for each of the 4 rows (2 float4 each)
        float4 xa[4], xb[4];
        #pragma unroll
        for (int r = 0; r < 4; ++r) {
            long long row = wave_base + r * 16 + rr;
            if (full || row < (long long)B) {
                long long bi = row * (DD / 4) + q * 4 + pass * 2;
                xa[r] = x4[bi];
                xb[r] = x4[bi + 1];
            } else {
                xa[r] = make_float4(0.f, 0.f, 0.f, 0.f);
                xb[r] = xa[r];
            }
        }
        #pragma unroll
        for (int d2 = 0; d2 < 8; ++d2) {
            const int dd = pass * 8 + d2;
            float4 w0 = W4[(dd * 4 + q) * 4 + 0];
            float4 w1 = W4[(dd * 4 + q) * 4 + 1];
            float4 w2 = W4[(dd * 4 + q) * 4 + 2];
            float4 w3 = W4[(dd * 4 + q) * 4 + 3];
            const float wf[JJ] = {w0.x, w0.y, w0.z, w0.w,
                                  w1.x, w1.y, w1.z, w1.w,
                                  w2.x, w2.y, w2.z, w2.w,
                                  w3.x, w3.y, w3.z, w3.w};
            #pragma unroll
            for (int r = 0; r < 4; ++r) {
                float xs = (d2 < 4) ? f4c(xa[r], d2) : f4c(xb[r], d2 - 4);
                #pragma unroll
                for (int j = 0; j < JJ; ++j)
                    acc[r][j] = fmaf(xs, wf[j], acc[r][j]);
            }
        }
    }

    // quad butterfly reduce: every lane ends with the full 64-d sum for all 4 rows
    #pragma unroll
    for (int r = 0; r < 4; ++r)
        #pragma unroll
        for (int j = 0; j < JJ; ++j) {
            float v = acc[r][j];
            v += __shfl_xor(v, 1, 64);
            v += __shfl_xor(v, 2, 64);
            acc[r][j] = v;
        }

    // lane q takes row-group r = q (static select, no dynamic indexing)
    float aj[JJ];
    #pragma unroll
    for (int j = 0; j < JJ; ++j) aj[j] = acc[0][j];
    #pragma unroll
    for (int r = 1; r < 4; ++r)
        #pragma unroll
        for (int j = 0; j < JJ; ++j)
            if (q == r) aj[j] = acc[r][j];

    float bl[JJ];
    #pragma unroll
    for (int g = 0; g < 4; ++g)
        reinterpret_cast<float4*>(bl)[g] = reinterpret_cast<const float4*>(bsl)[g];

    float h[JJ];
    #pragma unroll
    for (int j = 0; j < JJ; ++j) {
        float z = aj[j] + bl[j];
        h[j] = 1.0f / (1.0f + __expf(-z));
    }

    // f(17)=f(18)=1; i=16..1: neg_i = (i==3||i==7)?1:1-h[i-1]; f(i)=h*f(i+1)+neg*f(i+2)
    float f1 = 1.0f, f2 = 1.0f;
    #pragma unroll
    for (int i = JJ; i >= 1; --i) {
        float hj = h[i - 1];
        float neg = (i == 3 || i == 7) ? 1.0f : (1.0f - hj);
        float fi = fmaf(hj, f1, neg * f2);
        f2 = f1;
        f1 = fi;
    }

    long long orow = wave_base + q * 16 + rr;   // 64 consecutive rows per wave
    if (full || orow < (long long)B) out[orow] = f1;
}

extern "C" void kernel_launch(void* const* d_in, const int* in_sizes, int n_in,
                              void* d_out, int out_size, void* d_ws, size_t ws_size,
                              hipStream_t stream) {
    const float* x  = (const float*)d_in[0];
    const float* Ws = (const float*)d_in[1];
    const float* bs = (const float*)d_in[2];
    float* out = (float*)d_out;

    const int B = in_sizes[0] / DD;
    const int grid = (B + 255) / 256;

    net_circuit_kernel<<<grid, BLOCK, 0, stream>>>(x, Ws, bs, out, B);
}

// Round 3
// 68.693 us; speedup vs baseline: 20.2979x; 1.0563x over previous
//
#include <hip/hip_runtime.h>

#define BLOCK 256
#define DD 64
#define JJ 16

__device__ __forceinline__ float f4c(const float4& v, int i) {
    return i == 0 ? v.x : i == 1 ? v.y : i == 2 ? v.z : v.w;
}

__global__ __launch_bounds__(BLOCK, 2) void net_circuit_kernel(
    const float* __restrict__ x, const float* __restrict__ Ws,
    const float* __restrict__ bs, float* __restrict__ out, int B)
{
    // W slot map: slot(d) = (d&7)*8 + (d>>3).
    // Inner loop reads d = pass*32 + q*8 + d2  ->  slot = d2*8 + pass*4 + q:
    // the quad's 4 addresses are 64B apart -> banks 16 apart -> 2-way (free).
    __shared__ float Wl[DD * JJ];
    __shared__ __align__(16) float bsl[JJ];

    const int tid = threadIdx.x;
    for (int idx = tid; idx < DD * JJ; idx += BLOCK) {
        int d = idx >> 4, j = idx & 15;
        int slot = (d & 7) * 8 + (d >> 3);
        Wl[slot * JJ + j] = Ws[(j >> 2) * (DD * 4) + d * 4 + (j & 3)];
    }
    if (tid < JJ) bsl[tid] = bs[tid];
    __syncthreads();

    const int q  = tid & 3;          // quarter-of-pass this lane owns
    const int rr = (tid >> 2) & 15;  // row-within-group
    const int wid = tid >> 6;
    const long long wave_base = (long long)blockIdx.x * 256 + (long long)wid * 64;
    const bool full = (wave_base + 64 <= (long long)B);

    const float4* __restrict__ x4 = reinterpret_cast<const float4*>(x);
    const float4* __restrict__ W4 = reinterpret_cast<const float4*>(Wl);

    float acc[4][JJ];
    #pragma unroll
    for (int r = 0; r < 4; ++r)
        #pragma unroll
        for (int j = 0; j < JJ; ++j) acc[r][j] = 0.0f;

    #pragma unroll
    for (int pass = 0; pass < 2; ++pass) {
        // lane q reads floats [pass*32 + q*8, +8) of each row:
        // a quad covers one full 128B line per row per pass (no split lines)
        float4 xa[4], xb[4];
        #pragma unroll
        for (int r = 0; r < 4; ++r) {
            long long row = wave_base + r * 16 + rr;
            if (full || row < (long long)B) {
                long long bi = row * (DD / 4) + pass * 8 + q * 2;
                xa[r] = x4[bi];
                xb[r] = x4[bi + 1];
            } else {
                xa[r] = make_float4(0.f, 0.f, 0.f, 0.f);
                xb[r] = xa[r];
            }
        }
        #pragma unroll
        for (int d2 = 0; d2 < 8; ++d2) {
            const int slot = d2 * 8 + pass * 4 + q;   // = slot(d), d = pass*32+q*8+d2
            float4 w0 = W4[slot * 4 + 0];
            float4 w1 = W4[slot * 4 + 1];
            float4 w2 = W4[slot * 4 + 2];
            float4 w3 = W4[slot * 4 + 3];
            const float wf[JJ] = {w0.x, w0.y, w0.z, w0.w,
                                  w1.x, w1.y, w1.z, w1.w,
                                  w2.x, w2.y, w2.z, w2.w,
                                  w3.x, w3.y, w3.z, w3.w};
            #pragma unroll
            for (int r = 0; r < 4; ++r) {
                float xs = (d2 < 4) ? f4c(xa[r], d2) : f4c(xb[r], d2 - 4);
                #pragma unroll
                for (int j = 0; j < JJ; ++j)
                    acc[r][j] = fmaf(xs, wf[j], acc[r][j]);
            }
        }
    }

    // quad butterfly: every lane gets the full 64-d sum for all 4 row-groups
    #pragma unroll
    for (int r = 0; r < 4; ++r)
        #pragma unroll
        for (int j = 0; j < JJ; ++j) {
            float v = acc[r][j];
            v += __shfl_xor(v, 1, 64);
            v += __shfl_xor(v, 2, 64);
            acc[r][j] = v;
        }

    // lane q takes row-group r = q (static predicated select, no dyn indexing)
    float aj[JJ];
    #pragma unroll
    for (int j = 0; j < JJ; ++j) aj[j] = acc[0][j];
    #pragma unroll
    for (int r = 1; r < 4; ++r)
        #pragma unroll
        for (int j = 0; j < JJ; ++j)
            if (q == r) aj[j] = acc[r][j];

    float bl[JJ];
    #pragma unroll
    for (int g = 0; g < 4; ++g)
        reinterpret_cast<float4*>(bl)[g] = reinterpret_cast<const float4*>(bsl)[g];

    float h[JJ];
    #pragma unroll
    for (int j = 0; j < JJ; ++j) {
        float z = aj[j] + bl[j];
        h[j] = 1.0f / (1.0f + __expf(-z));
    }

    // f(17)=f(18)=1; i=16..1: neg_i=(i==3||i==7)?1:1-h[i-1]; f(i)=h*f(i+1)+neg*f(i+2)
    float f1 = 1.0f, f2 = 1.0f;
    #pragma unroll
    for (int i = JJ; i >= 1; --i) {
        float hj = h[i - 1];
        float neg = (i == 3 || i == 7) ? 1.0f : (1.0f - hj);
        float fi = fmaf(hj, f1, neg * f2);
        f2 = f1;
        f1 = fi;
    }

    long long orow = wave_base + q * 16 + rr;   // 64 consecutive rows per wave
    if (full || orow < (long long)B) out[orow] = f1;
}

extern "C" void kernel_launch(void* const* d_in, const int* in_sizes, int n_in,
                              void* d_out, int out_size, void* d_ws, size_t ws_size,
                              hipStream_t stream) {
    const float* x  = (const float*)d_in[0];
    const float* Ws = (const float*)d_in[1];
    const float* bs = (const float*)d_in[2];
    float* out = (float*)d_out;

    const int B = in_sizes[0] / DD;
    const int grid = (B + 255) / 256;

    net_circuit_kernel<<<grid, BLOCK, 0, stream>>>(x, Ws, bs, out, B);
}